// Round 8
// baseline (1291.668 us; speedup 1.0000x reference)
//
#include <hip/hip_runtime.h>

// TemporalAttentionDecoder_three_step: B=512, T=64, M=P=256. in f32, out f32.
// R15: 1046us. VALU 52%, occ 47%, VGPR 56, clean. Falsified: occupancy(R10),
//      L2 traffic(R8vsR9: 2x traffic = only +6%), coalescing(R11/12), stream
//      latency(R14). Remaining stall: ALL 16 waves share ONE barrier domain ->
//      whole CU stalls at each phase boundary in lockstep.
// R16: two independent barrier domains per CU. NROW=1, NTH=512, grid=512 ->
//      2 blocks/CU. LDS slimmed to ~45KB by DELETING e16T: final ct is
//      recomputed once from global E with f32 beta (better precision).
//      Step keeps R15's light shape, 3 barriers: A(Wd+Whh stream, full-k per
//      thread -> gate outputs direct to gg[1024], no partial combine) |
//      B1(tanh/l, lane=t, 32m/thr) | G(in-wave softmax+ytil+gates, j<256).
//      Domain A's barrier/L2 stalls overlap domain B's issue. wg=512 also
//      unlocks VGPR>64 (the 64-wall was wg=1024-specific) for stream MLP.
// f32 state: creg (j<256); f16: h,c,y1,weights; dots accumulate f32.

typedef unsigned short u16;
typedef unsigned int u32;
typedef _Float16 half_t;
typedef half_t h2 __attribute__((ext_vector_type(2)));

#define BB 512
#define TT 64
#define MM 256
#define YS 264   // y1l row stride (u16); measured conflict-free (R6/R7)
#define NTH 512

// ws layout (u16), all k-blocked n-major [kb][n][8]:
//   WdT8 [64kb][256n][8]  @ 0       (131072)
//   WhhT8[32kb][1024n][8] @ 131072  (262144)
//   WyT8 [64kb][256n][8]  @ 393216  (131072)
#define WD16_OFF  0
#define WHH16_OFF 131072
#define WY16_OFF  393216
#define WQ_ELEMS  524288
#define WQ_BYTES  (WQ_ELEMS * 2)

struct H8 { h2 p[4]; };   // 16B = 8 f16

#if defined(__has_builtin)
#if __has_builtin(__builtin_amdgcn_fdot2)
#define FDOT2(a, b, c) __builtin_amdgcn_fdot2((a), (b), (c), false)
#endif
#endif
#ifndef FDOT2
__device__ __forceinline__ float FDOT2(h2 a, h2 b, float c) {
  return c + (float)a[0] * (float)b[0] + (float)a[1] * (float)b[1];
}
#endif

__device__ __forceinline__ float dot8(const H8 w, const H8 a, float acc) {
  acc = FDOT2(w.p[0], a.p[0], acc);
  acc = FDOT2(w.p[1], a.p[1], acc);
  acc = FDOT2(w.p[2], a.p[2], acc);
  acc = FDOT2(w.p[3], a.p[3], acc);
  return acc;
}
__device__ __forceinline__ u16 f2h(float f) {
  union { half_t h; u16 u; } x; x.h = (half_t)f; return x.u;
}
__device__ __forceinline__ void unpackH8(const H8 v, float f[8]) {
#pragma unroll
  for (int i = 0; i < 8; ++i) f[i] = (float)v.p[i >> 1][i & 1];
}
__device__ __forceinline__ void ldf8(const float* p, float f[8]) {
  float4 a = *(const float4*)p;
  float4 b = *(const float4*)(p + 4);
  f[0]=a.x; f[1]=a.y; f[2]=a.z; f[3]=a.w;
  f[4]=b.x; f[5]=b.y; f[6]=b.z; f[7]=b.w;
}
__device__ __forceinline__ float tanh_fast(float x) {
  float e = __builtin_amdgcn_exp2f(x * 2.885390081777927f);
  return 1.0f - 2.0f * __builtin_amdgcn_rcpf(1.0f + e);
}
__device__ __forceinline__ float sigmoid_fast(float x) {
  float e = __builtin_amdgcn_exp2f(x * -1.4426950408889634f);
  return __builtin_amdgcn_rcpf(1.0f + e);
}

// ---- prep: f32 -> f16, k-blocked n-major ----
__global__ __launch_bounds__(256) void prep_kernel(
    const float* __restrict__ Wd, const float* __restrict__ Whh,
    const float* __restrict__ Wy, u16* __restrict__ o) {
  int i = blockIdx.x * 256 + threadIdx.x;   // 0..524287
  float v;
  if (i < WHH16_OFF) {
    int ki = i & 7, n = (i >> 3) & 255, kb = i >> 11;
    v = Wd[n * 512 + kb * 8 + ki];
  } else if (i < WY16_OFF) {
    int r = i - WHH16_OFF;
    int ki = r & 7, n = (r >> 3) & 1023, kb = r >> 13;
    v = Whh[n * 256 + kb * 8 + ki];
  } else {
    int r = i - WY16_OFF;
    int ki = r & 7, n = (r >> 3) & 255, kb = r >> 11;
    v = Wy[n * 512 + kb * 8 + ki];
  }
  o[i] = f2h(v);
}

template <int WQ>
__global__ __launch_bounds__(NTH) void scan_kernel(
    const float* __restrict__ E,      // (B,T,M)
    const float* __restrict__ yin,    // (B,T,1)
    const float* __restrict__ tar,    // (B,2)
    const int*   __restrict__ train,  // (1)
    const void*  __restrict__ Wd_q,   // WQ1: WdT8 f16 | WQ0: f32 row-major
    const float* __restrict__ Wd_b,
    const float* __restrict__ Ud_w,   // (256,256) f32
    const float* __restrict__ vd_w,
    const float* __restrict__ wt_w,   // (257)
    const float* __restrict__ wt_b,
    const void*  __restrict__ Wy_q,
    const float* __restrict__ Wy_b,
    const float* __restrict__ vy_w,
    const float* __restrict__ vy_b,
    const float* __restrict__ Wih,    // (1024)
    const void*  __restrict__ Whh_q,
    const float* __restrict__ bih,
    const float* __restrict__ bhh,
    float* __restrict__ out)          // (3*B)
{
  __shared__ __align__(16) u16   y1l[TT * YS];   // 33.8KB f16 y1
  __shared__ __align__(16) u32   hs16[256];      // h pairs [0,128), c [128,256)
  __shared__ __align__(16) u32   ctx16p[128];    // final ct f16 pairs
  __shared__ __align__(16) float px1[2][MM];     // x1 halves; head parts reuse
  __shared__ __align__(16) float gg[1024];       // gate pre-acts (i,f,g,o)
  __shared__ __align__(16) float lpart[8][TT];
  __shared__ __align__(16) float bet[TT];        // final beta (f32)
  __shared__ __align__(16) float ysh[TT];
  __shared__ __align__(16) float ewl[TT];        // ew[t] = E[t].wt
  __shared__ float red[8];
  __shared__ float sc[1];

  const int j    = threadIdx.x;        // 0..511
  const int n    = j & 255;            // output index
  const int half = j >> 8;             // k-half / seg selector
  const int wv   = j >> 6;             // wave 0..7
  const int b    = blockIdx.x;         // one batch row per block

  if (j < 256) hs16[j] = 0;
  float creg = 0.f;                    // live in j<256 threads

  // gate constants (consumed by j<256)
  const float wih0 = Wih[n],       wih1 = Wih[n + 256];
  const float wih2 = Wih[n + 512], wih3 = Wih[n + 768];
  const float bb0 = bih[n]       + bhh[n];
  const float bb1 = bih[n + 256] + bhh[n + 256];
  const float bb2 = bih[n + 512] + bhh[n + 512];
  const float bb3 = bih[n + 768] + bhh[n + 768];
  const float wtM = wt_w[MM], wtb = wt_b[0];

  // ---- stage yin + ew[t] = E[t].wt (loop-invariant) ----
  if (j < TT) {
    const int t = j;
    ysh[t] = yin[(size_t)b * TT + t];
    const float* __restrict__ Er = E + ((size_t)b * TT + t) * MM;
    float acc = 0.f;
    for (int m0 = 0; m0 < MM; m0 += 8) {
      float e[8], w[8];
      ldf8(Er + m0, e); ldf8(wt_w + m0, w);
#pragma unroll
      for (int m = 0; m < 8; ++m) acc = fmaf(e[m], w[m], acc);
    }
    ewl[t] = acc;
  }

  // ---- y1 into LDS: thread (half,n): t-half, column n ----
  {
    const float* __restrict__ Eb = E + (size_t)b * TT * MM;
    const float* __restrict__ Uj = Ud_w + (size_t)n * MM;
    for (int t0 = half * 32; t0 < half * 32 + 32; t0 += 16) {
      float acc[16];
#pragma unroll
      for (int i = 0; i < 16; ++i) acc[i] = 0.f;
      for (int m0 = 0; m0 < MM; m0 += 8) {
        float w[8]; ldf8(Uj + m0, w);
#pragma unroll
        for (int tt = 0; tt < 16; ++tt) {
          float e[8]; ldf8(Eb + (size_t)(t0 + tt) * MM + m0, e);
#pragma unroll
          for (int mm = 0; mm < 8; ++mm) acc[tt] = fmaf(e[mm], w[mm], acc[tt]);
        }
      }
#pragma unroll
      for (int tt = 0; tt < 16; ++tt)
        y1l[(t0 + tt) * YS + n] = f2h(acc[tt]);
    }
  }
  __syncthreads();

  // ---- gates: torch LSTMCell order i,f,g,o; j<256 threads ----
  auto gates_apply = [&](float gi, float gf, float gG, float go, float ytil) {
    gi += ytil * wih0 + bb0;
    gf += ytil * wih1 + bb1;
    gG += ytil * wih2 + bb2;
    go += ytil * wih3 + bb3;
    float c = sigmoid_fast(gf) * creg + sigmoid_fast(gi) * tanh_fast(gG);
    float h = sigmoid_fast(go) * tanh_fast(c);
    creg = c;
    u16* hsu = (u16*)hs16;
    hsu[n] = f2h(h);
    hsu[256 + n] = f2h(c);
  };

  // ---- S2: Whh@h, full k, outputs j and j+512 -> gg (all threads) ----
  auto whh_gg = [&]() {
    float g1 = 0.f, g2 = 0.f;
    if (WQ) {
      const u16* __restrict__ pw = (const u16*)Whh_q + (size_t)j * 8;
#pragma unroll 4
      for (int kb = 0; kb < 32; ++kb) {
        H8 w1 = *(const H8*)pw;
        H8 w2 = *(const H8*)(pw + 4096);  // j+512 offset = 512*8
        pw += 8192;
        H8 hv = *(const H8*)&hs16[kb * 4];
        g1 = dot8(w1, hv, g1);
        g2 = dot8(w2, hv, g2);
      }
    } else {
      const float* __restrict__ p1 = (const float*)Whh_q + (size_t)j * 256;
      const float* __restrict__ p2 = (const float*)Whh_q +
                                     ((size_t)j + 512) * 256;
#pragma unroll 2
      for (int kb = 0; kb < 32; ++kb) {
        H8 hv = *(const H8*)&hs16[kb * 4];
        float hf[8]; unpackH8(hv, hf);
        float w1[8], w2[8];
        ldf8(p1 + kb * 8, w1); ldf8(p2 + kb * 8, w2);
#pragma unroll
        for (int m = 0; m < 8; ++m) {
          g1 = fmaf(hf[m], w1[m], g1);
          g2 = fmaf(hf[m], w2[m], g2);
        }
      }
    }
    gg[j] = g1;
    gg[j + 512] = g2;
  };

  // ---- G: gates from gg + ytil (j<256) ----
  auto gates_from_gg = [&](float ytil) {
    gates_apply(gg[n], gg[n + 256], gg[n + 512], gg[n + 768], ytil);
  };

  // ---- head: (seg=half) h-seg / ct-seg dots -> out[idx*B+b], sc ----
  auto head_store = [&](int outIdx) {
    float p = 0.f;
    const u32* st = half ? ctx16p : hs16;
    if (WQ) {
      const u16* pw = (const u16*)Wy_q + ((size_t)(half * 32) * 256 + n) * 8;
#pragma unroll 2
      for (int kb = 0; kb < 32; ++kb) {
        H8 w = *(const H8*)pw; pw += 2048;
        H8 s = *(const H8*)&st[kb * 4];
        p = dot8(w, s, p);
      }
    } else {
      const float* W = (const float*)Wy_q + (size_t)n * 512 + half * 256;
#pragma unroll 2
      for (int kb = 0; kb < 32; ++kb) {
        H8 sv = *(const H8*)&st[kb * 4];
        float sf[8]; unpackH8(sv, sf);
        float w[8]; ldf8(W + kb * 8, w);
#pragma unroll
        for (int i = 0; i < 8; ++i) p = fmaf(sf[i], w[i], p);
      }
    }
    px1[half][n] = p;
    __syncthreads();
    if (j < 256) {
      float q = (px1[0][n] + px1[1][n] + Wy_b[n]) * vy_w[n];
#pragma unroll
      for (int off = 32; off; off >>= 1) q += __shfl_xor(q, off, 64);
      if ((j & 63) == 0) red[wv] = q;
    }
    __syncthreads();
    if (j == 0) {
      float o = red[0] + red[1] + red[2] + red[3] + vy_b[0];
      out[(size_t)outIdx * BB + b] = o;
      sc[0] = o;
    }
    __syncthreads();
  };

  // ================= scan over T steps =================
  for (int step = 0; step < TT; ++step) {
    // ---- A: S1 (x1 k-half) + S2 (Whh full-k) ----
    {
      float ax = 0.f;
      if (WQ) {
        const u16* pd = (const u16*)Wd_q + ((size_t)(half * 32) * 256 + n) * 8;
#pragma unroll 4
        for (int i = 0; i < 32; ++i) {
          H8 w = *(const H8*)pd; pd += 2048;
          H8 s = *(const H8*)&hs16[(half * 32 + i) * 4];
          ax = dot8(w, s, ax);
        }
      } else {
        const float* pd = (const float*)Wd_q + (size_t)n * 512 + half * 256;
#pragma unroll 2
        for (int i = 0; i < 32; ++i) {
          H8 sv = *(const H8*)&hs16[(half * 32 + i) * 4];
          float sf[8]; unpackH8(sv, sf);
          float w[8]; ldf8(pd + i * 8, w);
#pragma unroll
          for (int m = 0; m < 8; ++m) ax = fmaf(sf[m], w[m], ax);
        }
      }
      if (half == 0) ax += Wd_b[n];
      px1[half][n] = ax;
      whh_gg();
    }
    __syncthreads();

    // ---- B1: l[t] partials; thread = (e8=wv, t); 32 m each ----
    {
      const int t = j & 63;
      const int mb = wv * 32;
      const u16* __restrict__ yrow = &y1l[t * YS + mb];
      const float* __restrict__ xh = &px1[0][mb];
      const float* __restrict__ xc = &px1[1][mb];
      const float* __restrict__ vp = vd_w + mb;
      float lp = 0.f;
#pragma unroll
      for (int m0 = 0; m0 < 32; m0 += 8) {
        H8 yv = *(const H8*)(yrow + m0);
        float yf[8]; unpackH8(yv, yf);
        float xf[8]; ldf8(xh + m0, xf);
        float xg[8]; ldf8(xc + m0, xg);
        float vf[8]; ldf8(vp + m0, vf);
#pragma unroll
        for (int mm = 0; mm < 8; ++mm) {
          float z = tanh_fast(xf[mm] + xg[mm] + yf[mm]);
          lp = fmaf(z, vf[mm], lp);
        }
      }
      lpart[wv][t] = lp;
    }
    __syncthreads();

    // ---- G: in-wave softmax + ytil + gates (waves 0-3) ----
    if (j < 256) {
      const int t = j & 63;
      float l = lpart[0][t] + lpart[1][t] + lpart[2][t] + lpart[3][t] +
                lpart[4][t] + lpart[5][t] + lpart[6][t] + lpart[7][t];
      float mx = l;
#pragma unroll
      for (int off = 32; off; off >>= 1) mx = fmaxf(mx, __shfl_xor(mx, off, 64));
      float e = __builtin_amdgcn_exp2f((l - mx) * 1.4426950408889634f);
      float se = e, sy = e * ewl[t];
#pragma unroll
      for (int off = 32; off; off >>= 1) {
        se += __shfl_xor(se, off, 64);
        sy += __shfl_xor(sy, off, 64);
      }
      float yt = sy * __builtin_amdgcn_rcpf(se) + ysh[step] * wtM + wtb;
      gates_from_gg(yt);
    }
    __syncthreads();
  }

  // ================= finals =================
  // final beta (f32) from last step's lpart (wave 0)
  if (j < TT) {
    const int t = j;
    float l = lpart[0][t] + lpart[1][t] + lpart[2][t] + lpart[3][t] +
              lpart[4][t] + lpart[5][t] + lpart[6][t] + lpart[7][t];
    float mx = l;
#pragma unroll
    for (int off = 32; off; off >>= 1) mx = fmaxf(mx, __shfl_xor(mx, off, 64));
    float e = __builtin_amdgcn_exp2f((l - mx) * 1.4426950408889634f);
    float sm = e;
#pragma unroll
    for (int off = 32; off; off >>= 1) sm += __shfl_xor(sm, off, 64);
    bet[t] = e * __builtin_amdgcn_rcpf(sm);
  }
  __syncthreads();

  // ct[n] = sum_t bet[t]*E[t][n] from GLOBAL E (f32; coalesced per t)
  if (j < 256) {
    const float* __restrict__ Eb = E + (size_t)b * TT * MM + n;
    float acc = 0.f;
#pragma unroll 8
    for (int t = 0; t < TT; ++t) acc = fmaf(bet[t], Eb[(size_t)t * MM], acc);
    ((u16*)ctx16p)[n] = f2h(acc);
    float p = acc * wt_w[n];
#pragma unroll
    for (int off = 32; off; off >>= 1) p += __shfl_xor(p, off, 64);
    if ((j & 63) == 0) red[wv] = p;
  }
  __syncthreads();
  const float ctd = red[0] + red[1] + red[2] + red[3];

  head_store(0);  // y_Tp1 (sc holds it for train==0 feedback)

  const int tr = train[0];
  for (int e = 0; e < 2; ++e) {
    whh_gg();               // all threads: Whh@h -> gg
    __syncthreads();
    if (j < 256) {
      float inp = tr ? tar[(size_t)b * 2 + e] : sc[0];
      float yt = ctd + inp * wtM + wtb;
      gates_from_gg(yt);
    }
    __syncthreads();
    head_store(1 + e);
  }
}

extern "C" void kernel_launch(void* const* d_in, const int* in_sizes, int n_in,
                              void* d_out, int out_size, void* d_ws, size_t ws_size,
                              hipStream_t stream) {
  const float* E     = (const float*)d_in[0];
  const float* yin   = (const float*)d_in[1];
  const float* tar   = (const float*)d_in[2];
  const int*   train = (const int*)d_in[3];
  const float* Wd_w  = (const float*)d_in[4];
  const float* Wd_b  = (const float*)d_in[5];
  const float* Ud_w  = (const float*)d_in[6];
  const float* vd_w  = (const float*)d_in[7];
  const float* wt_w  = (const float*)d_in[8];
  const float* wt_b  = (const float*)d_in[9];
  const float* Wy_w  = (const float*)d_in[10];
  const float* Wy_b  = (const float*)d_in[11];
  const float* vy_w  = (const float*)d_in[12];
  const float* vy_b  = (const float*)d_in[13];
  const float* Wih   = (const float*)d_in[14];
  const float* Whh   = (const float*)d_in[15];
  const float* bih   = (const float*)d_in[16];
  const float* bhh   = (const float*)d_in[17];

  float* out = (float*)d_out;

  if (ws_size >= (size_t)WQ_BYTES) {
    u16* wq = (u16*)d_ws;
    prep_kernel<<<dim3(WQ_ELEMS / 256), dim3(256), 0, stream>>>(
        Wd_w, Whh, Wy_w, wq);
    scan_kernel<1><<<dim3(BB), dim3(NTH), 0, stream>>>(
        E, yin, tar, train, wq + WD16_OFF, Wd_b, Ud_w, vd_w, wt_w, wt_b,
        wq + WY16_OFF, Wy_b, vy_w, vy_b, Wih, wq + WHH16_OFF, bih, bhh, out);
  } else {
    scan_kernel<0><<<dim3(BB), dim3(NTH), 0, stream>>>(
        E, yin, tar, train, Wd_w, Wd_b, Ud_w, vd_w, wt_w, wt_b,
        Wy_w, Wy_b, vy_w, vy_b, Wih, Whh, bih, bhh, out);
  }

  (void)in_sizes; (void)n_in; (void)out_size;
}